// Round 5
// baseline (3565.164 us; speedup 1.0000x reference)
//
#include <hip/hip_runtime.h>
#include <hip/hip_bf16.h>

#define BB 64
#define NN 256
#define DD 512
#define EE 10

typedef __bf16 bf16x8 __attribute__((ext_vector_type(8)));
typedef unsigned short ushort8v __attribute__((ext_vector_type(8)));
typedef unsigned int uint4v __attribute__((ext_vector_type(4)));
typedef unsigned int uint2v __attribute__((ext_vector_type(2)));
typedef float floatx4 __attribute__((ext_vector_type(4)));
typedef float floatx16 __attribute__((ext_vector_type(16)));

typedef __attribute__((address_space(3))) unsigned short lds_us;
typedef const __attribute__((address_space(1))) unsigned short glb_us;

__device__ __forceinline__ unsigned short f2b(float f) {
    union { float f; unsigned u; } x; x.f = f;
    unsigned r = x.u + 0x7FFFu + ((x.u >> 16) & 1u);
    return (unsigned short)(r >> 16);
}
__device__ __forceinline__ float b2f(unsigned short u) {
    union { unsigned u; float f; } x; x.u = ((unsigned)u) << 16;
    return x.f;
}
// pack two rounded bf16 (hi=a, lo=b) from f32 bit patterns via byte-perm
__device__ __forceinline__ unsigned pack_bf16(float a, float b) {
    union { float f; unsigned u; } xa, xb2; xa.f = a; xb2.f = b;
    return __builtin_amdgcn_perm(xa.u + 0x8000u, xb2.u + 0x8000u, 0x07060302u);
}

// ---------------- K0a: W_edge/W_self -> Wf in 32x32x16 MFMA-B fragment order.
__global__ void k_wconv(const float* __restrict__ W_edge,
                        const float* __restrict__ W_self,
                        unsigned short* __restrict__ Wf) {
    int t = blockIdx.x * 256 + threadIdx.x;   // grid 1408 -> 360448 exact
    int lane  = t & 63;
    int kstep = (t >> 6) & 31;
    int cfg   = (t >> 11) & 15;
    int e     = t >> 15;                      // 0..10
    int dout = cfg * 32 + (lane & 31);
    int k    = kstep * 16 + (lane >> 5) * 8;
    const float* src = (e < EE) ? (W_edge + ((size_t)e * DD + dout) * DD + k)
                                : (W_self + (size_t)dout * DD + k);
    ushort8v o;
    #pragma unroll
    for (int j = 0; j < 8; j++) o[j] = f2b(src[j]);
    *(ushort8v*)(Wf + (size_t)t * 8) = o;
}

// ---------------- K0b: pack graph bits + recip(neigh). One block per (b,n).
__global__ void k_graph(const int* __restrict__ adj, const int* __restrict__ mask,
                        unsigned* __restrict__ packed, float* __restrict__ recip) {
    int b = blockIdx.x >> 8;
    int n = blockIdx.x & 255;
    int lane = threadIdx.x & 63;
    int wv   = threadIdx.x >> 6;   // 0..3
    int m = wv * 64 + lane;
    int ok = (mask[b * NN + n] != 0) & (mask[b * NN + m] != 0) & (m != n);
    __shared__ int cnt_s[4];
    int total = 0;
    #pragma unroll
    for (int e = 0; e < EE; e++) {
        int a = adj[(((size_t)e * BB + b) * NN + n) * NN + m];
        int bit = ok & (a != 0);
        unsigned long long bal = __ballot(bit);
        if (lane == 0) {
            unsigned* dst = packed + (((size_t)e * BB + b) * NN + n) * 8 + wv * 2;
            dst[0] = (unsigned)bal;
            dst[1] = (unsigned)(bal >> 32);
        }
        total += bit;
    }
    for (int off = 32; off; off >>= 1) total += __shfl_down(total, off);
    if (lane == 0) cnt_s[wv] = total;
    __syncthreads();
    if (threadIdx.x == 0) {
        int c = cnt_s[0] + cnt_s[1] + cnt_s[2] + cnt_s[3];
        recip[b * NN + n] = 1.0f / (float)(c < 1 ? 1 : c);
    }
}

// ---------------- K1a: gate w = sigmoid(node . W_nw + b). One wave per (b,n).
template<int TI>
__global__ void k_gate(const float* __restrict__ xf, const unsigned short* __restrict__ xbin,
                       const float* __restrict__ W_nw, const float* __restrict__ b_nw,
                       float* __restrict__ w_buf, float* __restrict__ w_out) {
    int idx = blockIdx.x * 4 + (threadIdx.x >> 6);
    int lane = threadIdx.x & 63;
    size_t base = (size_t)idx * DD + lane * 8;
    const floatx4* wp = (const floatx4*)(W_nw + lane * 8);
    floatx4 w0 = wp[0], w1 = wp[1];
    float s = 0.f;
    if (TI == 0) {
        const floatx4* xp = (const floatx4*)(xf + base);
        floatx4 a0 = xp[0], a1 = xp[1];
        #pragma unroll
        for (int j = 0; j < 4; j++) s += a0[j] * w0[j] + a1[j] * w1[j];
    } else {
        ushort8v u = *(const ushort8v*)(xbin + base);
        #pragma unroll
        for (int j = 0; j < 8; j++) {
            float wj = (j < 4) ? w0[j] : w1[j - 4];
            s += b2f(u[j]) * wj;
        }
    }
    for (int off = 32; off; off >>= 1) s += __shfl_down(s, off);
    if (lane == 0) {
        float v = 1.f / (1.f + __expf(-(s + b_nw[0])));
        w_buf[idx] = v;
        int b = idx >> 8, n = idx & 255;
        w_out[(b * 2 + TI) * NN + n] = v;
    }
}

// ---------------- K1b: build wTf (32x32 frag order) = w[b][m]*node[b][m][d], bf16.
template<int TI>
__global__ void k_transf(const float* __restrict__ xf, const unsigned short* __restrict__ xbin,
                         const float* __restrict__ w_buf,
                         unsigned short* __restrict__ wTf, unsigned short* __restrict__ xb0) {
    int bid = blockIdx.x;              // 64*4*8 = 2048
    int b  = bid >> 5;
    int nt = (bid >> 3) & 3;           // 64-m slab
    int dt = bid & 7;                  // 64-d slab
    __shared__ float tile[64][65];
    __shared__ float ws[64];
    int j  = threadIdx.x & 63;         // d
    int i0 = threadIdx.x >> 6;
    if (threadIdx.x < 64) ws[threadIdx.x] = w_buf[b * NN + nt * 64 + threadIdx.x];
    #pragma unroll
    for (int ii = 0; ii < 16; ii++) {
        int i = i0 * 16 + ii;          // m local
        size_t gi = ((size_t)b * NN + nt * 64 + i) * DD + dt * 64 + j;
        float v = (TI == 0) ? xf[gi] : b2f(xbin[gi]);
        tile[i][j] = v;
        if (TI == 0) xb0[gi] = f2b(v);
    }
    __syncthreads();
    int lane = threadIdx.x & 63;
    int l31 = lane & 31, hi = lane >> 5;
    #pragma unroll
    for (int cc = 0; cc < 2; cc++) {
        int c = cc * 4 + (threadIdx.x >> 6);   // 0..7: (msl = c>>1, dbl = c&1)
        int msl = c >> 1, dbl = c & 1;
        ushort8v o;
        #pragma unroll
        for (int jj = 0; jj < 8; jj++) {
            int m_loc = msl * 16 + hi * 8 + jj;
            int d_loc = dbl * 32 + l31;
            o[jj] = f2b(tile[m_loc][d_loc] * ws[m_loc]);
        }
        size_t idx = (((size_t)b * 16 + nt * 4 + msl) * 16 + dt * 2 + dbl) * 64 + lane;
        *(ushort8v*)(wTf + idx * 8) = o;
    }
}

// ---------------- K2: e-outer / dc-inner; 80 KB LDS -> 2 blocks/CU; frag-order sTf.
// Block 512 thr = 8 waves. Tile: 128 n (h half) x 256 dout (ct half). Grid 256.
// bid: ct = bid&1 (pinned per XCD), p = (bid>>1)&3, b = p*16 + ((bid>>3)&15), h = bid>>7.
template<int TI>
__global__ __launch_bounds__(512, 4)
void k2_heavy(const unsigned short* __restrict__ wTf,   // 32x32 frag order
              const unsigned short* __restrict__ xb,    // [B][N][D] bf16 (self A)
              const unsigned short* __restrict__ Wf,    // 32x32 frag order [11]
              const unsigned* __restrict__ packed,      // [E][B][N][8]
              const float* __restrict__ recip,          // [B][N]
              const float* __restrict__ b_self,         // [D]
              unsigned short* __restrict__ out_bf16,    // t=0
              float* __restrict__ out_f32) {            // t=1
    __shared__ __attribute__((aligned(16))) unsigned short sWT[32 * 512]; // 32 KB
    __shared__ __attribute__((aligned(16))) unsigned short sWf[32 * 512]; // 32 KB
    __shared__ __attribute__((aligned(16))) unsigned short sTf[16 * 512]; // 16 KB

    int bid = blockIdx.x;
    int ct = bid & 1;                        // dout half; fixed per XCD (bid mod 8)
    int p  = (bid >> 1) & 3;
    int b  = p * 16 + ((bid >> 3) & 15);
    int h  = bid >> 7;                       // 128-n half
    int w = threadIdx.x >> 6, lane = threadIdx.x & 63;
    int l31 = lane & 31, hi = lane >> 5;
    // stage-1 role: one 32d x 32n frag of T^T
    int s1_d  = w & 1;               // 32d within dc-chunk
    int s1_nb = w >> 1;              // 32n band (0..3)
    int n1 = s1_nb * 32 + l31;       // block-local n (lane col in stage-1 C)
    float rn = recip[b * NN + h * 128 + n1];
    // stage-2 role: 64 n x 64 dout
    int nh2 = w & 1;                 // 64-n half
    int dh4 = w >> 1;                // 64-dout quarter (0..3)

    floatx16 acc2[2][2];             // [na][cb]
    #pragma unroll
    for (int i = 0; i < 2; i++)
        #pragma unroll
        for (int jj = 0; jj < 2; jj++)
            #pragma unroll
            for (int q = 0; q < 16; q++) acc2[i][jj][q] = 0.f;

    auto stage_sWT = [&](int dc) {
        #pragma unroll
        for (int it = 0; it < 4; it++) {
            int c = it * 8 + w;                 // 0..31: ms = c>>1, dbl = c&1
            const unsigned short* g = wTf +
                ((((size_t)b * 16 + (c >> 1)) * 16 + dc * 2 + (c & 1)) * 64 + lane) * 8;
            __builtin_amdgcn_global_load_lds((glb_us*)g, (lds_us*)&sWT[c * 512], 16, 0, 0);
        }
    };
    auto stage_sWf = [&](int e, int dc) {
        #pragma unroll
        for (int it = 0; it < 4; it++) {
            int c = it * 8 + w;                 // 0..31: cf8 = c>>2, kk = c&3
            const unsigned short* g = Wf +
                ((((size_t)e * 16 + ct * 8 + (c >> 2)) * 32 + dc * 4 + (c & 3)) * 64 + lane) * 8;
            __builtin_amdgcn_global_load_lds((glb_us*)g, (lds_us*)&sWf[c * 512], 16, 0, 0);
        }
    };

    // prime: wnode chunk for step 0 (sWf issued at top of each step)
    stage_sWT(0);

    bf16x8 Bg[16];    // stage-1 B (expanded G bits), refreshed once per e

    #pragma unroll 1
    for (int s = 0; s < 88; s++) {
        int e = s >> 3, dc = s & 7;
        // ---- issue this step's W chunk, then drain both staging streams ----
        stage_sWf(e, dc);
        asm volatile("s_waitcnt vmcnt(0)" ::: "memory");
        asm volatile("s_barrier" ::: "memory");
        if (e < EE) {
            // ---- per-e: load packed bits + expand B fragments ----
            if (dc == 0) {
                const uint4v* pp = (const uint4v*)(packed +
                    (((size_t)e * BB + b) * NN + h * 128 + n1) * 8);
                uint4v pa = pp[0], pb = pp[1];
                unsigned pw[8] = {pa[0], pa[1], pa[2], pa[3], pb[0], pb[1], pb[2], pb[3]};
                #pragma unroll
                for (int ks = 0; ks < 16; ks++) {
                    int byi = ks * 2 + hi;
                    unsigned byte = (pw[byi >> 2] >> ((byi & 3) * 8)) & 0xFFu;
                    uint4v av;
                    #pragma unroll
                    for (int pp2 = 0; pp2 < 4; pp2++) {
                        unsigned t = (byte >> (2 * pp2)) & 3u;
                        unsigned u = (t | (t << 15)) & 0x10001u;
                        av[pp2] = u * 0x3F80u;
                    }
                    Bg[ks] = __builtin_bit_cast(bf16x8, av);
                }
            }
            // ---- stage 1: T^T frag (32d x 32n), K=256 over m ----
            floatx16 acc3;
            #pragma unroll
            for (int q = 0; q < 16; q++) acc3[q] = 0.f;
            #pragma unroll
            for (int ks = 0; ks < 16; ks++) {
                bf16x8 afr = __builtin_bit_cast(bf16x8,
                    *(const ushort8v*)&sWT[(ks * 2 + s1_d) * 512 + lane * 8]);
                acc3 = __builtin_amdgcn_mfma_f32_32x32x16_bf16(afr, Bg[ks], acc3, 0, 0, 0);
            }
            // scale by recip(n), pack, write into fragment-order sTf (4x b64)
            #pragma unroll
            for (int g = 0; g < 4; g++) {
                uint2v pk;
                pk[0] = pack_bf16(acc3[g * 4 + 1] * rn, acc3[g * 4 + 0] * rn);
                pk[1] = pack_bf16(acc3[g * 4 + 3] * rn, acc3[g * 4 + 2] * rn);
                int slot = (((s1_d * 2 + (g >> 1)) * 4 + s1_nb) * 64 + (g & 1) * 32 + l31);
                *(uint2v*)&sTf[slot * 8 + 4 * hi] = pk;
            }
            // ---- mid sync: sTf visible; sWT dead ----
            asm volatile("s_waitcnt lgkmcnt(0)" ::: "memory");
            asm volatile("s_barrier" ::: "memory");
            // prefetch next wnode chunk during stage-2 (single buffer, now free)
            if (s + 1 < 80) stage_sWT((s + 1) & 7);
            // ---- stage 2: acc2 += T(64n x 64d) @ W chunk ----
            #pragma unroll
            for (int kk = 0; kk < 4; kk++) {
                bf16x8 bfr[2];
                #pragma unroll
                for (int cb = 0; cb < 2; cb++)
                    bfr[cb] = __builtin_bit_cast(bf16x8, *(const ushort8v*)
                        &sWf[(((dh4 * 2 + cb) * 4 + kk) * 64 + lane) * 8]);
                #pragma unroll
                for (int na = 0; na < 2; na++) {
                    int nb = nh2 * 2 + na;
                    bf16x8 afr = __builtin_bit_cast(bf16x8, *(const ushort8v*)
                        &sTf[((kk * 4 + nb) * 64 + lane) * 8]);
                    #pragma unroll
                    for (int cb = 0; cb < 2; cb++)
                        acc2[na][cb] = __builtin_amdgcn_mfma_f32_32x32x16_bf16(
                            afr, bfr[cb], acc2[na][cb], 0, 0, 0);
                }
            }
        } else {
            // ---- self path: A direct from xb ----
            #pragma unroll
            for (int kk = 0; kk < 4; kk++) {
                bf16x8 bfr[2];
                #pragma unroll
                for (int cb = 0; cb < 2; cb++)
                    bfr[cb] = __builtin_bit_cast(bf16x8, *(const ushort8v*)
                        &sWf[(((dh4 * 2 + cb) * 4 + kk) * 64 + lane) * 8]);
                #pragma unroll
                for (int na = 0; na < 2; na++) {
                    bf16x8 afr = __builtin_bit_cast(bf16x8, *(const ushort8v*)(xb +
                        ((size_t)(b * NN + h * 128 + nh2 * 64 + na * 32 + l31)) * DD +
                        dc * 64 + kk * 16 + hi * 8));
                    #pragma unroll
                    for (int cb = 0; cb < 2; cb++)
                        acc2[na][cb] = __builtin_amdgcn_mfma_f32_32x32x16_bf16(
                            afr, bfr[cb], acc2[na][cb], 0, 0, 0);
                }
            }
        }
    }
    // ---- epilogue: +b_self, relu, store (C rows=n, cols=dout) ----
    #pragma unroll
    for (int cb = 0; cb < 2; cb++) {
        int col = ct * 256 + dh4 * 64 + cb * 32 + l31;
        float bs = b_self[col];
        #pragma unroll
        for (int na = 0; na < 2; na++) {
            #pragma unroll
            for (int rg = 0; rg < 16; rg++) {
                int row = h * 128 + nh2 * 64 + na * 32 + (rg & 3) + 8 * (rg >> 2) + 4 * hi;
                float v = acc2[na][cb][rg] + bs;
                v = v > 0.f ? v : 0.f;
                size_t gi = ((size_t)b * NN + row) * DD + col;
                if (TI == 0) out_bf16[gi] = f2b(v);
                else         out_f32[gi] = v;
            }
        }
    }
}

extern "C" void kernel_launch(void* const* d_in, const int* in_sizes, int n_in,
                              void* d_out, int out_size, void* d_ws, size_t ws_size,
                              hipStream_t stream) {
    const float* node   = (const float*)d_in[0];
    const float* W_nw   = (const float*)d_in[1];
    const float* b_nw   = (const float*)d_in[2];
    const float* W_self = (const float*)d_in[3];
    const float* b_self = (const float*)d_in[4];
    const float* W_edge = (const float*)d_in[5];
    const int*   mask   = (const int*)d_in[6];
    const int*   adj    = (const int*)d_in[7];
    float* out = (float*)d_out;
    float* out_w = out + (size_t)BB * NN * DD;   // all_weight region [B][2][N]

    char* ws = (char*)d_ws;
    size_t off = 0;
    unsigned short* Wf    = (unsigned short*)(ws + off); off += (size_t)11 * DD * DD * 2;      // 5.77 MB
    unsigned short* wTf   = (unsigned short*)(ws + off); off += (size_t)BB * DD * NN * 2;      // 16.78 MB
    unsigned short* xb0   = (unsigned short*)(ws + off); off += (size_t)BB * NN * DD * 2;      // 16.78 MB
    unsigned short* xb1   = (unsigned short*)(ws + off); off += (size_t)BB * NN * DD * 2;      // 16.78 MB
    unsigned*       packed= (unsigned*)(ws + off);       off += (size_t)EE * BB * NN * 8 * 4;  // 5.24 MB
    float*          recip = (float*)(ws + off);          off += (size_t)BB * NN * 4;
    float*          w_buf = (float*)(ws + off);          off += (size_t)BB * NN * 4;

    k_wconv<<<dim3(1408), dim3(256), 0, stream>>>(W_edge, W_self, Wf);
    k_graph<<<dim3(16384), dim3(256), 0, stream>>>(adj, mask, packed, recip);

    // iteration 0
    k_gate<0><<<dim3(4096), dim3(256), 0, stream>>>(node, nullptr, W_nw, b_nw, w_buf, out_w);
    k_transf<0><<<dim3(2048), dim3(256), 0, stream>>>(node, nullptr, w_buf, wTf, xb0);
    k2_heavy<0><<<dim3(256), dim3(512), 0, stream>>>(wTf, xb0, Wf, packed, recip, b_self, xb1, nullptr);

    // iteration 1
    k_gate<1><<<dim3(4096), dim3(256), 0, stream>>>(nullptr, xb1, W_nw, b_nw, w_buf, out_w);
    k_transf<1><<<dim3(2048), dim3(256), 0, stream>>>(nullptr, xb1, w_buf, wTf, xb0 /*unused*/);
    k2_heavy<1><<<dim3(256), dim3(512), 0, stream>>>(wTf, xb1, Wf, packed, recip, b_self, nullptr, out);
}

// Round 6
// 698.191 us; speedup vs baseline: 5.1063x; 5.1063x over previous
//
#include <hip/hip_runtime.h>
#include <hip/hip_bf16.h>

#define BB 64
#define NN 256
#define DD 512
#define EE 10

typedef __bf16 bf16x8 __attribute__((ext_vector_type(8)));
typedef unsigned short ushort8v __attribute__((ext_vector_type(8)));
typedef unsigned int uint4v __attribute__((ext_vector_type(4)));
typedef unsigned int uint2v __attribute__((ext_vector_type(2)));
typedef float floatx4 __attribute__((ext_vector_type(4)));
typedef float floatx16 __attribute__((ext_vector_type(16)));

typedef __attribute__((address_space(3))) unsigned short lds_us;
typedef const __attribute__((address_space(1))) unsigned short glb_us;

__device__ __forceinline__ unsigned short f2b(float f) {
    union { float f; unsigned u; } x; x.f = f;
    unsigned r = x.u + 0x7FFFu + ((x.u >> 16) & 1u);
    return (unsigned short)(r >> 16);
}
__device__ __forceinline__ float b2f(unsigned short u) {
    union { unsigned u; float f; } x; x.u = ((unsigned)u) << 16;
    return x.f;
}
// pack two rounded bf16 (hi=a, lo=b) from f32 bit patterns via byte-perm
__device__ __forceinline__ unsigned pack_bf16(float a, float b) {
    union { float f; unsigned u; } xa, xb2; xa.f = a; xb2.f = b;
    return __builtin_amdgcn_perm(xa.u + 0x8000u, xb2.u + 0x8000u, 0x07060302u);
}

// ---------------- K0a: W_edge/W_self -> Wf in 32x32x16 MFMA-B fragment order.
__global__ void k_wconv(const float* __restrict__ W_edge,
                        const float* __restrict__ W_self,
                        unsigned short* __restrict__ Wf) {
    int t = blockIdx.x * 256 + threadIdx.x;   // grid 1408 -> 360448 exact
    int lane  = t & 63;
    int kstep = (t >> 6) & 31;
    int cfg   = (t >> 11) & 15;
    int e     = t >> 15;                      // 0..10
    int dout = cfg * 32 + (lane & 31);
    int k    = kstep * 16 + (lane >> 5) * 8;
    const float* src = (e < EE) ? (W_edge + ((size_t)e * DD + dout) * DD + k)
                                : (W_self + (size_t)dout * DD + k);
    ushort8v o;
    #pragma unroll
    for (int j = 0; j < 8; j++) o[j] = f2b(src[j]);
    *(ushort8v*)(Wf + (size_t)t * 8) = o;
}

// ---------------- K0b: pack graph bits + recip(neigh). One block per (b,n).
__global__ void k_graph(const int* __restrict__ adj, const int* __restrict__ mask,
                        unsigned* __restrict__ packed, float* __restrict__ recip) {
    int b = blockIdx.x >> 8;
    int n = blockIdx.x & 255;
    int lane = threadIdx.x & 63;
    int wv   = threadIdx.x >> 6;   // 0..3
    int m = wv * 64 + lane;
    int ok = (mask[b * NN + n] != 0) & (mask[b * NN + m] != 0) & (m != n);
    __shared__ int cnt_s[4];
    int total = 0;
    #pragma unroll
    for (int e = 0; e < EE; e++) {
        int a = adj[(((size_t)e * BB + b) * NN + n) * NN + m];
        int bit = ok & (a != 0);
        unsigned long long bal = __ballot(bit);
        if (lane == 0) {
            unsigned* dst = packed + (((size_t)e * BB + b) * NN + n) * 8 + wv * 2;
            dst[0] = (unsigned)bal;
            dst[1] = (unsigned)(bal >> 32);
        }
        total += bit;
    }
    for (int off = 32; off; off >>= 1) total += __shfl_down(total, off);
    if (lane == 0) cnt_s[wv] = total;
    __syncthreads();
    if (threadIdx.x == 0) {
        int c = cnt_s[0] + cnt_s[1] + cnt_s[2] + cnt_s[3];
        recip[b * NN + n] = 1.0f / (float)(c < 1 ? 1 : c);
    }
}

// ---------------- K1 fused: gate + bf16 copy + frag-order wTf build.
// Grid 1024 = (b, ms): block handles 16 rows (n = ms*16..+16) x 512 d.
template<int TI>
__global__ __launch_bounds__(256)
void k_gt(const float* __restrict__ xf, const unsigned short* __restrict__ xbin,
          const float* __restrict__ W_nw, const float* __restrict__ b_nw,
          float* __restrict__ w_out, unsigned short* __restrict__ wTf,
          unsigned short* __restrict__ xb0) {
    int bid = blockIdx.x;
    int b  = bid >> 4;
    int ms = bid & 15;
    __shared__ float part[16][17];
    __shared__ float wsig[16];
    int t = threadIdx.x;
    int row = t >> 4;          // 0..15 local n
    int seg = t & 15;          // 32-d segment
    size_t g = ((size_t)(b * NN + ms * 16 + row)) * DD + seg * 32;
    float s = 0.f;
    if (TI == 0) {
        const floatx4* xp = (const floatx4*)(xf + g);
        const floatx4* wp = (const floatx4*)(W_nw + seg * 32);
        #pragma unroll
        for (int k = 0; k < 4; k++) {
            floatx4 a = xp[2 * k], c4 = xp[2 * k + 1];
            floatx4 wa = wp[2 * k], wc = wp[2 * k + 1];
            ushort8v u;
            #pragma unroll
            for (int j = 0; j < 4; j++) {
                s += a[j] * wa[j] + c4[j] * wc[j];
                u[j] = f2b(a[j]); u[4 + j] = f2b(c4[j]);
            }
            *(ushort8v*)(xb0 + g + k * 8) = u;
        }
    } else {
        const ushort8v* xp = (const ushort8v*)(xbin + g);
        const float* wp = W_nw + seg * 32;
        #pragma unroll
        for (int k = 0; k < 4; k++) {
            ushort8v u = xp[k];
            #pragma unroll
            for (int j = 0; j < 8; j++) s += b2f(u[j]) * wp[k * 8 + j];
        }
    }
    part[row][seg] = s;
    __syncthreads();
    if (t < 16) {
        float tot = 0.f;
        #pragma unroll
        for (int i = 0; i < 16; i++) tot += part[t][i];
        float v = 1.f / (1.f + __expf(-(tot + b_nw[0])));
        wsig[t] = v;
        w_out[(b * 2 + TI) * NN + ms * 16 + t] = v;
    }
    __syncthreads();
    // phase 2: write wTf frag-order (elem j = x[m=ms*16+hi*8+j][dd*32+l31] * w[m])
    #pragma unroll
    for (int c = 0; c < 4; c++) {
        int slot = t + 256 * c;          // 0..1023
        int dd_  = slot >> 6;            // 0..15
        int lane = slot & 63;
        int l31 = lane & 31, hi = lane >> 5;
        size_t xrow = ((size_t)(b * NN + ms * 16 + hi * 8)) * DD + dd_ * 32 + l31;
        float wv[8];
        ushort8v o;
        #pragma unroll
        for (int j = 0; j < 8; j++) {
            float xv = (TI == 0) ? xf[xrow + (size_t)j * DD] : b2f(xbin[xrow + (size_t)j * DD]);
            o[j] = f2b(xv * wsig[hi * 8 + j]);
        }
        (void)wv;
        *(ushort8v*)(wTf + ((((size_t)b * 16 + ms) * 16 + dd_) * 64 + lane) * 8) = o;
    }
}

// ---------------- K2: e-outer / dc-inner; dbuf sWf, frag-order sTf, split stage-1 chains.
// Block 512 thr = 8 waves, 1 block/CU. Tile: 128 n (h half) x 256 dout (ct half). Grid 256.
template<int TI>
__global__ __launch_bounds__(512, 2)
void k2_heavy(const unsigned short* __restrict__ wTf,   // 32x32 frag order
              const unsigned short* __restrict__ xb,    // [B][N][D] bf16 (self A)
              const unsigned short* __restrict__ Wf,    // 32x32 frag order [11]
              const unsigned* __restrict__ packed,      // [E][B][N][8]
              const float* __restrict__ recip,          // [B][N]
              const float* __restrict__ b_self,         // [D]
              unsigned short* __restrict__ out_bf16,    // t=0
              float* __restrict__ out_f32) {            // t=1
    __shared__ __attribute__((aligned(16))) unsigned short sWT[32 * 512];    // 32 KB
    __shared__ __attribute__((aligned(16))) unsigned short sWf[2][32 * 512]; // 64 KB
    __shared__ __attribute__((aligned(16))) unsigned short sTf[16 * 512];    // 16 KB

    int bid = blockIdx.x;
    int ct = bid & 1;                        // dout half
    int p  = (bid >> 1) & 3;
    int b  = p * 16 + ((bid >> 3) & 15);
    int h  = bid >> 7;                       // 128-n half
    int w = threadIdx.x >> 6, lane = threadIdx.x & 63;
    int l31 = lane & 31, hi = lane >> 5;
    // stage-1 role: one 32d x 32n frag of T^T
    int s1_d  = w & 1;               // 32d within dc-chunk
    int s1_nb = w >> 1;              // 32n band (0..3)
    int n1 = s1_nb * 32 + l31;       // block-local n (lane col in stage-1 C)
    float rn = recip[b * NN + h * 128 + n1];
    // stage-2 role: 64 n x 64 dout
    int nh2 = w & 1;                 // 64-n half
    int dh4 = w >> 1;                // 64-dout quarter (0..3)

    floatx16 acc2[2][2];             // [na][cb]
    #pragma unroll
    for (int i = 0; i < 2; i++)
        #pragma unroll
        for (int jj = 0; jj < 2; jj++)
            #pragma unroll
            for (int q = 0; q < 16; q++) acc2[i][jj][q] = 0.f;

    auto stage_sWT = [&](int dc) {
        #pragma unroll
        for (int it = 0; it < 4; it++) {
            int c = it * 8 + w;                 // 0..31: ms = c>>1, dbl = c&1
            const unsigned short* g = wTf +
                ((((size_t)b * 16 + (c >> 1)) * 16 + dc * 2 + (c & 1)) * 64 + lane) * 8;
            __builtin_amdgcn_global_load_lds((glb_us*)g, (lds_us*)&sWT[c * 512], 16, 0, 0);
        }
    };
    auto stage_sWf = [&](int e, int dc, int buf) {
        #pragma unroll
        for (int it = 0; it < 4; it++) {
            int c = it * 8 + w;                 // 0..31: cf8 = c>>2, kk = c&3
            const unsigned short* g = Wf +
                ((((size_t)e * 16 + ct * 8 + (c >> 2)) * 32 + dc * 4 + (c & 3)) * 64 + lane) * 8;
            __builtin_amdgcn_global_load_lds((glb_us*)g, (lds_us*)&sWf[buf][c * 512], 16, 0, 0);
        }
    };

    // prime step 0
    stage_sWT(0);
    stage_sWf(0, 0, 0);

    bf16x8 Bg[16];    // stage-1 B (expanded G bits), refreshed once per e

    #pragma unroll 1
    for (int s = 0; s < 88; s++) {
        int e = s >> 3, dc = s & 7, cur = s & 1;
        // ---- top sync: this step's sWf / sWT have landed ----
        asm volatile("s_waitcnt vmcnt(0)" ::: "memory");
        asm volatile("s_barrier" ::: "memory");
        // ---- issue next step's W chunk now: hidden behind the whole step ----
        if (s < 87) {
            int ns = s + 1;
            stage_sWf(ns >> 3, ns & 7, cur ^ 1);
        }
        if (e < EE) {
            // ---- per-e: load packed bits + expand B fragments ----
            if (dc == 0) {
                const uint4v* pp = (const uint4v*)(packed +
                    (((size_t)e * BB + b) * NN + h * 128 + n1) * 8);
                uint4v pa = pp[0], pb = pp[1];
                unsigned pw[8] = {pa[0], pa[1], pa[2], pa[3], pb[0], pb[1], pb[2], pb[3]};
                #pragma unroll
                for (int ks = 0; ks < 16; ks++) {
                    int byi = ks * 2 + hi;
                    unsigned byte = (pw[byi >> 2] >> ((byi & 3) * 8)) & 0xFFu;
                    uint4v av;
                    #pragma unroll
                    for (int pp2 = 0; pp2 < 4; pp2++) {
                        unsigned tt = (byte >> (2 * pp2)) & 3u;
                        unsigned u = (tt | (tt << 15)) & 0x10001u;
                        av[pp2] = u * 0x3F80u;
                    }
                    Bg[ks] = __builtin_bit_cast(bf16x8, av);
                }
            }
            // ---- stage 1: T^T frag (32d x 32n), K=256, TWO independent chains ----
            floatx16 acc3a, acc3b;
            #pragma unroll
            for (int q = 0; q < 16; q++) { acc3a[q] = 0.f; acc3b[q] = 0.f; }
            #pragma unroll
            for (int ks = 0; ks < 8; ks++) {
                bf16x8 afrA = __builtin_bit_cast(bf16x8,
                    *(const ushort8v*)&sWT[((2 * ks) * 2 + s1_d) * 512 + lane * 8]);
                bf16x8 afrB = __builtin_bit_cast(bf16x8,
                    *(const ushort8v*)&sWT[((2 * ks + 1) * 2 + s1_d) * 512 + lane * 8]);
                acc3a = __builtin_amdgcn_mfma_f32_32x32x16_bf16(afrA, Bg[2 * ks],     acc3a, 0, 0, 0);
                acc3b = __builtin_amdgcn_mfma_f32_32x32x16_bf16(afrB, Bg[2 * ks + 1], acc3b, 0, 0, 0);
            }
            // merge, scale by recip(n), pack, write frag-order sTf (4x b64)
            #pragma unroll
            for (int g = 0; g < 4; g++) {
                float v0 = (acc3a[g * 4 + 0] + acc3b[g * 4 + 0]) * rn;
                float v1 = (acc3a[g * 4 + 1] + acc3b[g * 4 + 1]) * rn;
                float v2 = (acc3a[g * 4 + 2] + acc3b[g * 4 + 2]) * rn;
                float v3 = (acc3a[g * 4 + 3] + acc3b[g * 4 + 3]) * rn;
                uint2v pk;
                pk[0] = pack_bf16(v1, v0);
                pk[1] = pack_bf16(v3, v2);
                int slot = (((s1_d * 2 + (g >> 1)) * 4 + s1_nb) * 64 + (g & 1) * 32 + l31);
                *(uint2v*)&sTf[slot * 8 + 4 * hi] = pk;
            }
            // ---- mid sync: sTf visible; sWT dead ----
            asm volatile("s_waitcnt lgkmcnt(0)" ::: "memory");
            asm volatile("s_barrier" ::: "memory");
            // prefetch next dc's wnode chunk during stage-2 (lands by next top drain)
            if (s + 1 < 80) stage_sWT((s + 1) & 7);
            // ---- stage 2: acc2 += T(64n x 64d) @ W chunk ----
            #pragma unroll
            for (int kk = 0; kk < 4; kk++) {
                bf16x8 bfr[2];
                #pragma unroll
                for (int cb = 0; cb < 2; cb++)
                    bfr[cb] = __builtin_bit_cast(bf16x8, *(const ushort8v*)
                        &sWf[cur][(((dh4 * 2 + cb) * 4 + kk) * 64 + lane) * 8]);
                #pragma unroll
                for (int na = 0; na < 2; na++) {
                    int nb = nh2 * 2 + na;
                    bf16x8 afr = __builtin_bit_cast(bf16x8, *(const ushort8v*)
                        &sTf[((kk * 4 + nb) * 64 + lane) * 8]);
                    #pragma unroll
                    for (int cb = 0; cb < 2; cb++)
                        acc2[na][cb] = __builtin_amdgcn_mfma_f32_32x32x16_bf16(
                            afr, bfr[cb], acc2[na][cb], 0, 0, 0);
                }
            }
        } else {
            // ---- self path: A direct from xb ----
            #pragma unroll
            for (int kk = 0; kk < 4; kk++) {
                bf16x8 bfr[2];
                #pragma unroll
                for (int cb = 0; cb < 2; cb++)
                    bfr[cb] = __builtin_bit_cast(bf16x8, *(const ushort8v*)
                        &sWf[cur][(((dh4 * 2 + cb) * 4 + kk) * 64 + lane) * 8]);
                #pragma unroll
                for (int na = 0; na < 2; na++) {
                    bf16x8 afr = __builtin_bit_cast(bf16x8, *(const ushort8v*)(xb +
                        ((size_t)(b * NN + h * 128 + nh2 * 64 + na * 32 + l31)) * DD +
                        dc * 64 + kk * 16 + hi * 8));
                    #pragma unroll
                    for (int cb = 0; cb < 2; cb++)
                        acc2[na][cb] = __builtin_amdgcn_mfma_f32_32x32x16_bf16(
                            afr, bfr[cb], acc2[na][cb], 0, 0, 0);
                }
            }
        }
    }
    // ---- epilogue: +b_self, relu, store (C rows=n, cols=dout) ----
    #pragma unroll
    for (int cb = 0; cb < 2; cb++) {
        int col = ct * 256 + dh4 * 64 + cb * 32 + l31;
        float bs = b_self[col];
        #pragma unroll
        for (int na = 0; na < 2; na++) {
            #pragma unroll
            for (int rg = 0; rg < 16; rg++) {
                int row = h * 128 + nh2 * 64 + na * 32 + (rg & 3) + 8 * (rg >> 2) + 4 * hi;
                float v = acc2[na][cb][rg] + bs;
                v = v > 0.f ? v : 0.f;
                size_t gi = ((size_t)b * NN + row) * DD + col;
                if (TI == 0) out_bf16[gi] = f2b(v);
                else         out_f32[gi] = v;
            }
        }
    }
}

extern "C" void kernel_launch(void* const* d_in, const int* in_sizes, int n_in,
                              void* d_out, int out_size, void* d_ws, size_t ws_size,
                              hipStream_t stream) {
    const float* node   = (const float*)d_in[0];
    const float* W_nw   = (const float*)d_in[1];
    const float* b_nw   = (const float*)d_in[2];
    const float* W_self = (const float*)d_in[3];
    const float* b_self = (const float*)d_in[4];
    const float* W_edge = (const float*)d_in[5];
    const int*   mask   = (const int*)d_in[6];
    const int*   adj    = (const int*)d_in[7];
    float* out = (float*)d_out;
    float* out_w = out + (size_t)BB * NN * DD;   // all_weight region [B][2][N]

    char* ws = (char*)d_ws;
    size_t off = 0;
    unsigned short* Wf    = (unsigned short*)(ws + off); off += (size_t)11 * DD * DD * 2;      // 5.77 MB
    unsigned short* wTf   = (unsigned short*)(ws + off); off += (size_t)BB * DD * NN * 2;      // 16.78 MB
    unsigned short* xb0   = (unsigned short*)(ws + off); off += (size_t)BB * NN * DD * 2;      // 16.78 MB
    unsigned short* xb1   = (unsigned short*)(ws + off); off += (size_t)BB * NN * DD * 2;      // 16.78 MB
    unsigned*       packed= (unsigned*)(ws + off);       off += (size_t)EE * BB * NN * 8 * 4;  // 5.24 MB
    float*          recip = (float*)(ws + off);          off += (size_t)BB * NN * 4;

    k_wconv<<<dim3(1408), dim3(256), 0, stream>>>(W_edge, W_self, Wf);
    k_graph<<<dim3(16384), dim3(256), 0, stream>>>(adj, mask, packed, recip);

    // iteration 0
    k_gt<0><<<dim3(1024), dim3(256), 0, stream>>>(node, nullptr, W_nw, b_nw, out_w, wTf, xb0);
    k2_heavy<0><<<dim3(256), dim3(512), 0, stream>>>(wTf, xb0, Wf, packed, recip, b_self, xb1, nullptr);

    // iteration 1
    k_gt<1><<<dim3(1024), dim3(256), 0, stream>>>(nullptr, xb1, W_nw, b_nw, out_w, wTf, nullptr);
    k2_heavy<1><<<dim3(256), dim3(512), 0, stream>>>(wTf, xb1, Wf, packed, recip, b_self, nullptr, out);
}